// Round 1
// baseline (1912.569 us; speedup 1.0000x reference)
//
#include <hip/hip_runtime.h>
#include <math.h>

// N=50000 nodes, E0=800000 edges (+N self loops), IN=128, H=8, C=8 (HC=64), ED=16, T=96

__device__ __forceinline__ unsigned fenc(float f) {
    unsigned u = __float_as_uint(f);
    return (u & 0x80000000u) ? ~u : (u | 0x80000000u);
}
__device__ __forceinline__ float fdec(unsigned e) {
    unsigned u = (e & 0x80000000u) ? (e & 0x7FFFFFFFu) : ~e;
    return __uint_as_float(u);
}

// ---------------- node projections: q,k,v (N x 64), a_node,b_node (N x 8) ----------------
// block = 256 threads handles 64 nodes; x tile staged in LDS; thread j owns one output
// column (208 active: 192 qkv + 8 a + 8 b), acc[64] nodes in registers, LDS reads broadcast.
__global__ __launch_bounds__(256) void k_proj(
    const float* __restrict__ x,
    const float* __restrict__ Wq, const float* __restrict__ Wk, const float* __restrict__ Wv,
    const float* __restrict__ compW,
    float* __restrict__ q, float* __restrict__ k, float* __restrict__ v,
    float* __restrict__ an, float* __restrict__ bn, int N)
{
    __shared__ float xt[64 * 128];
    const int n0 = blockIdx.x * 64;
    const int tid = threadIdx.x;
    for (int i = tid; i < 2048; i += 256) {          // 2048 float4 = 64x128 floats
        int row = i >> 5, c4 = i & 31;
        int n = n0 + row;
        float4 val = make_float4(0.f, 0.f, 0.f, 0.f);
        if (n < N) val = ((const float4*)(x + (size_t)n * 128))[c4];
        ((float4*)xt)[i] = val;
    }
    __syncthreads();
    if (tid >= 208) return;

    const float* wrow;
    if (tid < 192) {
        if (tid < 64)        wrow = Wq + tid * 128;
        else if (tid < 128)  wrow = Wk + (tid - 64) * 128;
        else                 wrow = Wv + (tid - 128) * 128;
    } else if (tid < 200)    wrow = compW + (tid - 192) * 256;        // first 128 cols
    else                     wrow = compW + (tid - 200) * 256 + 128;  // last 128 cols

    float acc[64];
    #pragma unroll
    for (int i = 0; i < 64; i++) acc[i] = 0.f;

    for (int k4 = 0; k4 < 32; k4++) {
        float4 w4 = ((const float4*)wrow)[k4];
        #pragma unroll
        for (int nn = 0; nn < 64; nn++) {
            float4 x4 = ((const float4*)xt)[nn * 32 + k4];
            acc[nn] += x4.x * w4.x + x4.y * w4.y + x4.z * w4.z + x4.w * w4.w;
        }
    }
    #pragma unroll
    for (int nn = 0; nn < 64; nn++) {
        int n = n0 + nn;
        if (n < N) {
            float r = acc[nn];
            if (tid < 64)        q[(size_t)n * 64 + tid] = r;
            else if (tid < 128)  k[(size_t)n * 64 + (tid - 64)] = r;
            else if (tid < 192)  v[(size_t)n * 64 + (tid - 128)] = r;
            else if (tid < 200)  an[(size_t)n * 8 + (tid - 192)] = r;
            else                 bn[(size_t)n * 8 + (tid - 200)] = r;
        }
    }
}

// ---------------- temporal profile normalization (ddof=1), one wave per node ----------------
__global__ __launch_bounds__(256) void k_tpn(const float* __restrict__ tp,
                                             float* __restrict__ tpn, int N)
{
    int wave = threadIdx.x >> 6;
    int lane = threadIdx.x & 63;
    int n = blockIdx.x * 4 + wave;
    if (n >= N) return;
    const float* row = tp + (size_t)n * 96;
    float v0 = row[lane];
    float v1 = (lane < 32) ? row[64 + lane] : 0.f;
    float s = v0 + v1, ss = v0 * v0 + v1 * v1;
    #pragma unroll
    for (int m = 1; m < 64; m <<= 1) { s += __shfl_xor(s, m); ss += __shfl_xor(ss, m); }
    float mean = s * (1.f / 96.f);
    float var = (ss - 96.f * mean * mean) * (1.f / 95.f);
    var = fmaxf(var, 0.f);
    float inv = 1.f / (sqrtf(var) + 1e-8f);
    float* orow = tpn + (size_t)n * 96;
    orow[lane] = (v0 - mean) * inv;
    if (lane < 32) orow[64 + lane] = (v1 - mean) * inv;
}

// ---------------- edge pass 1: alpha logits + segment max (8 lanes per edge, lane = head) ----
__global__ __launch_bounds__(256) void k_edge_alpha(
    const int* __restrict__ ei, const float* __restrict__ eattr,
    const float* __restrict__ tpn,
    const float* __restrict__ q, const float* __restrict__ k,
    const float* __restrict__ an, const float* __restrict__ bn,
    const float* __restrict__ We, const float* __restrict__ comp_b,
    float* __restrict__ alpha, unsigned* __restrict__ amax,
    int E0, int N)
{
    __shared__ float WeT[16 * 64];                    // [d][hc]
    const int tid = threadIdx.x;
    for (int i = tid; i < 1024; i += 256) {
        int d = i >> 6, hc = i & 63;
        WeT[i] = We[hc * 16 + d];
    }
    __syncthreads();
    const int E = E0 + N;
    const int e = blockIdx.x * 32 + (tid >> 3);
    if (e >= E) return;
    const int h = tid & 7;
    int src, dst;
    if (e < E0) { src = ei[e]; dst = ei[E0 + e]; }
    else        { src = e - E0; dst = src; }

    // correlation: lane h sums t in [12h, 12h+12)
    const float4* ts = (const float4*)(tpn + (size_t)src * 96 + h * 12);
    const float4* td = (const float4*)(tpn + (size_t)dst * 96 + h * 12);
    float cs = 0.f;
    #pragma unroll
    for (int i = 0; i < 3; i++) {
        float4 pa = ts[i], pb = td[i];
        cs += pa.x * pb.x + pa.y * pb.y + pa.z * pb.z + pa.w * pb.w;
    }
    cs += __shfl_xor(cs, 1); cs += __shfl_xor(cs, 2); cs += __shfl_xor(cs, 4);
    float corr = cs * (1.f / 96.f);

    // k fragment (head h of src)
    float kr[8];
    {
        const float4* kp = (const float4*)(k + (size_t)src * 64 + h * 8);
        float4 k0 = kp[0], k1 = kp[1];
        kr[0] = k0.x; kr[1] = k0.y; kr[2] = k0.z; kr[3] = k0.w;
        kr[4] = k1.x; kr[5] = k1.y; kr[6] = k1.z; kr[7] = k1.w;
    }
    float qk;
    {
        const float4* qp = (const float4*)(q + (size_t)dst * 64 + h * 8);
        float4 q0 = qp[0], q1 = qp[1];
        qk = q0.x * kr[0] + q0.y * kr[1] + q0.z * kr[2] + q0.w * kr[3]
           + q1.x * kr[4] + q1.y * kr[5] + q1.z * kr[6] + q1.w * kr[7];
    }

    float ear[16];
    if (e < E0) {
        const float4* ep = (const float4*)(eattr + (size_t)e * 16);
        #pragma unroll
        for (int i = 0; i < 4; i++) {
            float4 pa = ep[i];
            ear[i * 4] = pa.x; ear[i * 4 + 1] = pa.y; ear[i * 4 + 2] = pa.z; ear[i * 4 + 3] = pa.w;
        }
    } else {
        #pragma unroll
        for (int i = 0; i < 16; i++) ear[i] = 1.f;
    }

    // (ea @ We.T) . k  ==  sum_d ea[d] * (sum_c We[h*8+c][d] * kr[c])
    float efk = 0.f;
    #pragma unroll
    for (int d = 0; d < 16; d++) {
        float kw = 0.f;
        #pragma unroll
        for (int c = 0; c < 8; c++) kw += WeT[d * 64 + h * 8 + c] * kr[c];
        efk += ear[d] * kw;
    }

    float t = tanhf(an[(size_t)src * 8 + h] + bn[(size_t)dst * 8 + h] + comp_b[h]);
    float tsum = t;
    tsum += __shfl_xor(tsum, 1); tsum += __shfl_xor(tsum, 2); tsum += __shfl_xor(tsum, 4);
    float learned = tsum * (1.f / 8.f);

    float comp = 0.5f * corr + 0.5f * learned;
    float a = qk * 0.35355339059327373f + efk - 0.5f * comp;   // CW * (-comp), CW=0.5
    a = (a >= 0.f) ? a : 0.2f * a;                             // leaky relu
    alpha[(size_t)e * 8 + h] = a;
    atomicMax(&amax[(size_t)dst * 8 + h], fenc(a));
}

// ---------------- edge pass 2: exp, denom, unnormalized aggregation ----------------
__global__ __launch_bounds__(256) void k_edge_agg(
    const int* __restrict__ ei,
    const float* __restrict__ v,
    const float* __restrict__ alpha, const unsigned* __restrict__ amax,
    float* __restrict__ denom, float* __restrict__ agg,
    int E0, int N)
{
    const int tid = threadIdx.x;
    const int E = E0 + N;
    const int e = blockIdx.x * 32 + (tid >> 3);
    if (e >= E) return;
    const int h = tid & 7;
    int src, dst;
    if (e < E0) { src = ei[e]; dst = ei[E0 + e]; }
    else        { src = e - E0; dst = src; }

    float a = alpha[(size_t)e * 8 + h];
    float m = fdec(amax[(size_t)dst * 8 + h]);
    float ev = expf(a - m);
    atomicAdd(&denom[(size_t)dst * 8 + h], ev);
    const float4* vp = (const float4*)(v + (size_t)src * 64 + h * 8);
    float4 v0 = vp[0], v1 = vp[1];
    float* ag = agg + (size_t)dst * 64 + h * 8;
    atomicAdd(ag + 0, ev * v0.x); atomicAdd(ag + 1, ev * v0.y);
    atomicAdd(ag + 2, ev * v0.z); atomicAdd(ag + 3, ev * v0.w);
    atomicAdd(ag + 4, ev * v1.x); atomicAdd(ag + 5, ev * v1.y);
    atomicAdd(ag + 6, ev * v1.z); atomicAdd(ag + 7, ev * v1.w);
}

// ---------------- final: normalize per (n,h), apply Wo^T + bo ----------------
__global__ __launch_bounds__(256) void k_out(
    const float* __restrict__ agg, const float* __restrict__ denom,
    const float* __restrict__ Wo, const float* __restrict__ bo,
    float* __restrict__ out, int N)
{
    int gid = blockIdx.x * 256 + threadIdx.x;
    int n = gid >> 3, cp = gid & 7;
    if (n >= N) return;
    float rd[8];
    #pragma unroll
    for (int hh = 0; hh < 8; hh++) rd[hh] = 1.f / (denom[(size_t)n * 8 + hh] + 1e-16f);
    const float* ar = agg + (size_t)n * 64;
    const float* wr = Wo + cp * 64;
    float accv = bo[cp];
    #pragma unroll
    for (int i = 0; i < 64; i++) accv += ar[i] * rd[i >> 3] * wr[i];
    out[(size_t)n * 8 + cp] = accv;
}

extern "C" void kernel_launch(void* const* d_in, const int* in_sizes, int n_in,
                              void* d_out, int out_size, void* d_ws, size_t ws_size,
                              hipStream_t stream)
{
    const float* x     = (const float*)d_in[0];
    const int*   ei    = (const int*)d_in[1];
    const float* eattr = (const float*)d_in[2];
    const float* tp    = (const float*)d_in[3];
    const float* Wq    = (const float*)d_in[4];
    const float* Wk    = (const float*)d_in[5];
    const float* Wv    = (const float*)d_in[6];
    const float* We    = (const float*)d_in[7];
    const float* compW = (const float*)d_in[8];
    const float* compb = (const float*)d_in[9];
    const float* Wo    = (const float*)d_in[10];
    const float* bo    = (const float*)d_in[11];
    float* out = (float*)d_out;

    const int N  = in_sizes[0] / 128;
    const int E0 = in_sizes[1] / 2;
    const int E  = E0 + N;

    float* ws = (float*)d_ws;
    size_t off = 0;
    float* tpn   = ws + off; off += (size_t)N * 96;
    float* q     = ws + off; off += (size_t)N * 64;
    float* k     = ws + off; off += (size_t)N * 64;
    float* v     = ws + off; off += (size_t)N * 64;
    float* an    = ws + off; off += (size_t)N * 8;
    float* bn    = ws + off; off += (size_t)N * 8;
    float* alpha = ws + off; off += (size_t)E * 8;
    unsigned* amax = (unsigned*)(ws + off); off += (size_t)N * 8;
    float* denom = ws + off; off += (size_t)N * 8;
    float* agg   = ws + off; off += (size_t)N * 64;

    // zero amax (ordered encoding: 0 < any real), denom, agg — contiguous region
    hipMemsetAsync(amax, 0, (size_t)N * (8 + 8 + 64) * sizeof(float), stream);

    k_proj<<<(N + 63) / 64, 256, 0, stream>>>(x, Wq, Wk, Wv, compW, q, k, v, an, bn, N);
    k_tpn<<<(N + 3) / 4, 256, 0, stream>>>(tp, tpn, N);
    k_edge_alpha<<<(E + 31) / 32, 256, 0, stream>>>(ei, eattr, tpn, q, k, an, bn, We, compb,
                                                    alpha, amax, E0, N);
    k_edge_agg<<<(E + 31) / 32, 256, 0, stream>>>(ei, v, alpha, amax, denom, agg, E0, N);
    k_out<<<((size_t)N * 8 + 255) / 256, 256, 0, stream>>>(agg, denom, Wo, bo, out, N);
}

// Round 2
// 626.287 us; speedup vs baseline: 3.0538x; 3.0538x over previous
//
#include <hip/hip_runtime.h>
#include <math.h>

// N=50000 nodes, E0=800000 edges (+N self loops), IN=128, H=8, C=8 (HC=64), ED=16, T=96

// ---------------- node projections: q,k,v (N x 64), a_node,b_node (N x 8) ----------------
__global__ __launch_bounds__(256) void k_proj(
    const float* __restrict__ x,
    const float* __restrict__ Wq, const float* __restrict__ Wk, const float* __restrict__ Wv,
    const float* __restrict__ compW,
    float* __restrict__ q, float* __restrict__ k, float* __restrict__ v,
    float* __restrict__ an, float* __restrict__ bn, int N)
{
    __shared__ float xt[64 * 128];
    const int n0 = blockIdx.x * 64;
    const int tid = threadIdx.x;
    for (int i = tid; i < 2048; i += 256) {          // 2048 float4 = 64x128 floats
        int row = i >> 5, c4 = i & 31;
        int n = n0 + row;
        float4 val = make_float4(0.f, 0.f, 0.f, 0.f);
        if (n < N) val = ((const float4*)(x + (size_t)n * 128))[c4];
        ((float4*)xt)[i] = val;
    }
    __syncthreads();
    if (tid >= 208) return;

    const float* wrow;
    if (tid < 192) {
        if (tid < 64)        wrow = Wq + tid * 128;
        else if (tid < 128)  wrow = Wk + (tid - 64) * 128;
        else                 wrow = Wv + (tid - 128) * 128;
    } else if (tid < 200)    wrow = compW + (tid - 192) * 256;        // first 128 cols
    else                     wrow = compW + (tid - 200) * 256 + 128;  // last 128 cols

    float acc[64];
    #pragma unroll
    for (int i = 0; i < 64; i++) acc[i] = 0.f;

    for (int k4 = 0; k4 < 32; k4++) {
        float4 w4 = ((const float4*)wrow)[k4];
        #pragma unroll
        for (int nn = 0; nn < 64; nn++) {
            float4 x4 = ((const float4*)xt)[nn * 32 + k4];
            acc[nn] += x4.x * w4.x + x4.y * w4.y + x4.z * w4.z + x4.w * w4.w;
        }
    }
    #pragma unroll
    for (int nn = 0; nn < 64; nn++) {
        int n = n0 + nn;
        if (n < N) {
            float r = acc[nn];
            if (tid < 64)        q[(size_t)n * 64 + tid] = r;
            else if (tid < 128)  k[(size_t)n * 64 + (tid - 64)] = r;
            else if (tid < 192)  v[(size_t)n * 64 + (tid - 128)] = r;
            else if (tid < 200)  an[(size_t)n * 8 + (tid - 192)] = r;
            else                 bn[(size_t)n * 8 + (tid - 200)] = r;
        }
    }
}

// ---------------- temporal profile normalization (ddof=1), one wave per node ----------------
__global__ __launch_bounds__(256) void k_tpn(const float* __restrict__ tp,
                                             float* __restrict__ tpn, int N)
{
    int wave = threadIdx.x >> 6;
    int lane = threadIdx.x & 63;
    int n = blockIdx.x * 4 + wave;
    if (n >= N) return;
    const float* row = tp + (size_t)n * 96;
    float v0 = row[lane];
    float v1 = (lane < 32) ? row[64 + lane] : 0.f;
    float s = v0 + v1, ss = v0 * v0 + v1 * v1;
    #pragma unroll
    for (int m = 1; m < 64; m <<= 1) { s += __shfl_xor(s, m); ss += __shfl_xor(ss, m); }
    float mean = s * (1.f / 96.f);
    float var = (ss - 96.f * mean * mean) * (1.f / 95.f);
    var = fmaxf(var, 0.f);
    float inv = 1.f / (sqrtf(var) + 1e-8f);
    float* orow = tpn + (size_t)n * 96;
    orow[lane] = (v0 - mean) * inv;
    if (lane < 32) orow[64 + lane] = (v1 - mean) * inv;
}

// ---------------- CSR build: histogram / scan / scatter ----------------
__global__ __launch_bounds__(256) void k_hist(const int* __restrict__ ei,
                                              int* __restrict__ deg, int E0, int N)
{
    int e = blockIdx.x * 256 + threadIdx.x;
    int E = E0 + N;
    if (e >= E) return;
    int dst = (e < E0) ? ei[E0 + e] : (e - E0);
    atomicAdd(&deg[dst], 1);
}

__global__ __launch_bounds__(1024) void k_scan(const int* __restrict__ deg,
                                               int* __restrict__ row,
                                               int* __restrict__ cursor, int N)
{
    __shared__ int part[1024];
    int t = threadIdx.x;
    int chunk = (N + 1023) >> 10;
    int s0 = t * chunk;
    int s = 0;
    for (int i = 0; i < chunk; i++) {
        int idx = s0 + i;
        if (idx < N) s += deg[idx];
    }
    part[t] = s;
    __syncthreads();
    for (int off = 1; off < 1024; off <<= 1) {
        int vv = (t >= off) ? part[t - off] : 0;
        __syncthreads();
        part[t] += vv;
        __syncthreads();
    }
    int run = (t == 0) ? 0 : part[t - 1];
    for (int i = 0; i < chunk; i++) {
        int idx = s0 + i;
        if (idx < N) { row[idx] = run; cursor[idx] = run; run += deg[idx]; }
    }
    if (t == 1023) row[N] = part[1023];
}

__global__ __launch_bounds__(256) void k_scatter(const int* __restrict__ ei,
                                                 int* __restrict__ cursor,
                                                 int* __restrict__ csr, int E0, int N)
{
    int e = blockIdx.x * 256 + threadIdx.x;
    int E = E0 + N;
    if (e >= E) return;
    int dst = (e < E0) ? ei[E0 + e] : (e - E0);
    int pos = atomicAdd(&cursor[dst], 1);
    csr[pos] = e;
}

// ---------------- edge pass: alpha logits (8 lanes per edge, lane = head) ----
__global__ __launch_bounds__(256) void k_edge_alpha(
    const int* __restrict__ ei, const float* __restrict__ eattr,
    const float* __restrict__ tpn,
    const float* __restrict__ q, const float* __restrict__ k,
    const float* __restrict__ an, const float* __restrict__ bn,
    const float* __restrict__ We, const float* __restrict__ comp_b,
    float* __restrict__ alpha,
    int E0, int N)
{
    __shared__ float WeT[16 * 64];                    // [d][hc]
    const int tid = threadIdx.x;
    for (int i = tid; i < 1024; i += 256) {
        int d = i >> 6, hc = i & 63;
        WeT[i] = We[hc * 16 + d];
    }
    __syncthreads();
    const int E = E0 + N;
    const int e = blockIdx.x * 32 + (tid >> 3);
    if (e >= E) return;
    const int h = tid & 7;
    int src, dst;
    if (e < E0) { src = ei[e]; dst = ei[E0 + e]; }
    else        { src = e - E0; dst = src; }

    // correlation: lane h sums t in [12h, 12h+12)
    const float4* ts = (const float4*)(tpn + (size_t)src * 96 + h * 12);
    const float4* td = (const float4*)(tpn + (size_t)dst * 96 + h * 12);
    float cs = 0.f;
    #pragma unroll
    for (int i = 0; i < 3; i++) {
        float4 pa = ts[i], pb = td[i];
        cs += pa.x * pb.x + pa.y * pb.y + pa.z * pb.z + pa.w * pb.w;
    }
    cs += __shfl_xor(cs, 1); cs += __shfl_xor(cs, 2); cs += __shfl_xor(cs, 4);
    float corr = cs * (1.f / 96.f);

    // k fragment (head h of src)
    float kr[8];
    {
        const float4* kp = (const float4*)(k + (size_t)src * 64 + h * 8);
        float4 k0 = kp[0], k1 = kp[1];
        kr[0] = k0.x; kr[1] = k0.y; kr[2] = k0.z; kr[3] = k0.w;
        kr[4] = k1.x; kr[5] = k1.y; kr[6] = k1.z; kr[7] = k1.w;
    }
    float qk;
    {
        const float4* qp = (const float4*)(q + (size_t)dst * 64 + h * 8);
        float4 q0 = qp[0], q1 = qp[1];
        qk = q0.x * kr[0] + q0.y * kr[1] + q0.z * kr[2] + q0.w * kr[3]
           + q1.x * kr[4] + q1.y * kr[5] + q1.z * kr[6] + q1.w * kr[7];
    }

    float ear[16];
    if (e < E0) {
        const float4* ep = (const float4*)(eattr + (size_t)e * 16);
        #pragma unroll
        for (int i = 0; i < 4; i++) {
            float4 pa = ep[i];
            ear[i * 4] = pa.x; ear[i * 4 + 1] = pa.y; ear[i * 4 + 2] = pa.z; ear[i * 4 + 3] = pa.w;
        }
    } else {
        #pragma unroll
        for (int i = 0; i < 16; i++) ear[i] = 1.f;
    }

    // (ea @ We.T) . k  ==  sum_d ea[d] * (sum_c We[h*8+c][d] * kr[c])
    float efk = 0.f;
    #pragma unroll
    for (int d = 0; d < 16; d++) {
        float kw = 0.f;
        #pragma unroll
        for (int c = 0; c < 8; c++) kw += WeT[d * 64 + h * 8 + c] * kr[c];
        efk += ear[d] * kw;
    }

    float t = tanhf(an[(size_t)src * 8 + h] + bn[(size_t)dst * 8 + h] + comp_b[h]);
    float tsum = t;
    tsum += __shfl_xor(tsum, 1); tsum += __shfl_xor(tsum, 2); tsum += __shfl_xor(tsum, 4);
    float learned = tsum * (1.f / 8.f);

    float comp = 0.5f * corr + 0.5f * learned;
    float a = qk * 0.35355339059327373f + efk - 0.5f * comp;   // CW * (-comp), CW=0.5
    a = (a >= 0.f) ? a : 0.2f * a;                             // leaky relu
    alpha[(size_t)e * 8 + h] = a;
}

// ---------------- per-node: segment softmax + aggregation + Wo projection ----------------
// one wave per node; lane = h*8 + c owns output channel hc
__global__ __launch_bounds__(256) void k_node(
    const int* __restrict__ ei, const int* __restrict__ row, const int* __restrict__ csr,
    const float* __restrict__ alpha, const float* __restrict__ v,
    const float* __restrict__ Wo, const float* __restrict__ bo,
    float* __restrict__ out, int E0, int N)
{
    __shared__ float WoS[512];
    __shared__ float boS[8];
    const int tid = threadIdx.x;
    for (int i = tid; i < 512; i += 256) WoS[i] = Wo[i];
    if (tid < 8) boS[tid] = bo[tid];
    __syncthreads();
    const int wave = tid >> 6, lane = tid & 63;
    const int n = blockIdx.x * 4 + wave;
    if (n >= N) return;
    const int beg = row[n], end = row[n + 1];
    const int h = lane >> 3;

    // phase A: per-head max; lane = el*8 + hm handles edge stripe el for head hm
    float mx = -1e30f;
    for (int idx = beg + (lane >> 3); idx < end; idx += 8) {
        int e = csr[idx];
        mx = fmaxf(mx, alpha[(size_t)e * 8 + (lane & 7)]);
    }
    mx = fmaxf(mx, __shfl_xor(mx, 8));
    mx = fmaxf(mx, __shfl_xor(mx, 16));
    mx = fmaxf(mx, __shfl_xor(mx, 32));
    float mxh = __shfl(mx, h);   // lane h (h<8) holds head h's max

    // phase B: exp + denom + weighted V accumulation
    float acc = 0.f, dsum = 0.f;
    for (int base = beg; base < end; base += 64) {
        int cnt = min(64, end - base);
        int eid = 0, sv = 0;
        if (lane < cnt) {
            eid = csr[base + lane];
            sv = (eid < E0) ? ei[eid] : (eid - E0);
        }
        for (int j = 0; j < cnt; j++) {
            int e = __shfl(eid, j);
            int s = __shfl(sv, j);
            float a = alpha[(size_t)e * 8 + h];
            float ev = expf(a - mxh);
            dsum += ev;
            acc += ev * v[(size_t)s * 64 + lane];
        }
    }
    float outv = acc / (dsum + 1e-16f);

    // fused output projection: out[n][cp] = sum_hc outv[hc] * Wo[cp][hc] + bo[cp]
    float po[8];
    #pragma unroll
    for (int cp = 0; cp < 8; cp++) po[cp] = outv * WoS[cp * 64 + lane];
    #pragma unroll
    for (int m = 1; m < 64; m <<= 1) {
        #pragma unroll
        for (int cp = 0; cp < 8; cp++) po[cp] += __shfl_xor(po[cp], m);
    }
    if (lane < 8) out[(size_t)n * 8 + lane] = po[lane] + boS[lane];
}

extern "C" void kernel_launch(void* const* d_in, const int* in_sizes, int n_in,
                              void* d_out, int out_size, void* d_ws, size_t ws_size,
                              hipStream_t stream)
{
    const float* x     = (const float*)d_in[0];
    const int*   ei    = (const int*)d_in[1];
    const float* eattr = (const float*)d_in[2];
    const float* tp    = (const float*)d_in[3];
    const float* Wq    = (const float*)d_in[4];
    const float* Wk    = (const float*)d_in[5];
    const float* Wv    = (const float*)d_in[6];
    const float* We    = (const float*)d_in[7];
    const float* compW = (const float*)d_in[8];
    const float* compb = (const float*)d_in[9];
    const float* Wo    = (const float*)d_in[10];
    const float* bo    = (const float*)d_in[11];
    float* out = (float*)d_out;

    const int N  = in_sizes[0] / 128;
    const int E0 = in_sizes[1] / 2;
    const int E  = E0 + N;

    float* ws = (float*)d_ws;
    size_t off = 0;
    float* tpn   = ws + off; off += (size_t)N * 96;
    float* q     = ws + off; off += (size_t)N * 64;
    float* k     = ws + off; off += (size_t)N * 64;
    float* v     = ws + off; off += (size_t)N * 64;
    float* an    = ws + off; off += (size_t)N * 8;
    float* bn    = ws + off; off += (size_t)N * 8;
    float* alpha = ws + off; off += (size_t)E * 8;
    int* deg    = (int*)(ws + off); off += N;
    int* rowp   = (int*)(ws + off); off += N + 1;
    int* cursor = (int*)(ws + off); off += N;
    int* csr    = (int*)(ws + off); off += E;

    hipMemsetAsync(deg, 0, (size_t)N * sizeof(int), stream);

    k_hist<<<(E + 255) / 256, 256, 0, stream>>>(ei, deg, E0, N);
    k_scan<<<1, 1024, 0, stream>>>(deg, rowp, cursor, N);
    k_scatter<<<(E + 255) / 256, 256, 0, stream>>>(ei, cursor, csr, E0, N);

    k_proj<<<(N + 63) / 64, 256, 0, stream>>>(x, Wq, Wk, Wv, compW, q, k, v, an, bn, N);
    k_tpn<<<(N + 3) / 4, 256, 0, stream>>>(tp, tpn, N);
    k_edge_alpha<<<(E + 31) / 32, 256, 0, stream>>>(ei, eattr, tpn, q, k, an, bn, We, compb,
                                                    alpha, E0, N);
    k_node<<<(N + 3) / 4, 256, 0, stream>>>(ei, rowp, csr, alpha, v, Wo, bo, out, E0, N);
}

// Round 3
// 511.159 us; speedup vs baseline: 3.7416x; 1.2252x over previous
//
#include <hip/hip_runtime.h>
#include <math.h>

// N=50000 nodes, E0=800000 edges (+N self loops), IN=128, H=8, C=8 (HC=64), ED=16, T=96

struct __align__(8) US4 { unsigned short x, y, z, w; };

__device__ __forceinline__ unsigned short f2bf(float f) {
    unsigned u = __float_as_uint(f);
    unsigned r = (u + 0x7fffu + ((u >> 16) & 1u)) >> 16;
    return (unsigned short)r;
}
__device__ __forceinline__ float bf2f(unsigned short u) {
    return __uint_as_float(((unsigned)u) << 16);
}

// ---------------- node projections: q (f32), k,v (bf16), a_node,b_node (f32) ----------------
// 256 threads / 64 nodes; thread = (node-quarter sh, col-quad cq): 4 cols x 16 nodes each.
__global__ __launch_bounds__(256) void k_proj(
    const float* __restrict__ x,
    const float* __restrict__ Wq, const float* __restrict__ Wk, const float* __restrict__ Wv,
    const float* __restrict__ compW,
    float* __restrict__ q, unsigned short* __restrict__ kb, unsigned short* __restrict__ vb,
    float* __restrict__ an, float* __restrict__ bn, int N)
{
    __shared__ float xt[64 * 128];
    const int n0 = blockIdx.x * 64;
    const int tid = threadIdx.x;
    for (int i = tid; i < 2048; i += 256) {
        int row = i >> 5, c4 = i & 31;
        int n = n0 + row;
        float4 val = make_float4(0.f, 0.f, 0.f, 0.f);
        if (n < N) val = ((const float4*)(x + (size_t)n * 128))[c4];
        ((float4*)xt)[i] = val;
    }
    __syncthreads();
    if (tid >= 208) return;
    const int sh = tid / 52;          // node quarter (16 nodes)
    const int cq = tid % 52;          // column quad

    const float* wrow; int wstride;
    if (cq < 16)      { wrow = Wq + (size_t)cq * 4 * 128;          wstride = 128; }
    else if (cq < 32) { wrow = Wk + (size_t)(cq - 16) * 4 * 128;   wstride = 128; }
    else if (cq < 48) { wrow = Wv + (size_t)(cq - 32) * 4 * 128;   wstride = 128; }
    else if (cq < 50) { wrow = compW + (size_t)(cq - 48) * 4 * 256;       wstride = 256; }
    else              { wrow = compW + (size_t)(cq - 50) * 4 * 256 + 128; wstride = 256; }

    float acc[16][4];
    #pragma unroll
    for (int i = 0; i < 16; i++)
        #pragma unroll
        for (int j = 0; j < 4; j++) acc[i][j] = 0.f;

    const float4* xt4 = (const float4*)xt;
    for (int k4 = 0; k4 < 32; k4++) {
        float4 w0 = ((const float4*)(wrow + 0 * wstride))[k4];
        float4 w1 = ((const float4*)(wrow + 1 * wstride))[k4];
        float4 w2 = ((const float4*)(wrow + 2 * wstride))[k4];
        float4 w3 = ((const float4*)(wrow + 3 * wstride))[k4];
        #pragma unroll
        for (int nn = 0; nn < 16; nn++) {
            float4 x4 = xt4[(sh * 16 + nn) * 32 + k4];
            acc[nn][0] += x4.x * w0.x + x4.y * w0.y + x4.z * w0.z + x4.w * w0.w;
            acc[nn][1] += x4.x * w1.x + x4.y * w1.y + x4.z * w1.z + x4.w * w1.w;
            acc[nn][2] += x4.x * w2.x + x4.y * w2.y + x4.z * w2.z + x4.w * w2.w;
            acc[nn][3] += x4.x * w3.x + x4.y * w3.y + x4.z * w3.z + x4.w * w3.w;
        }
    }
    #pragma unroll
    for (int nn = 0; nn < 16; nn++) {
        int n = n0 + sh * 16 + nn;
        if (n >= N) continue;
        if (cq < 16) {
            float4 r = make_float4(acc[nn][0], acc[nn][1], acc[nn][2], acc[nn][3]);
            ((float4*)(q + (size_t)n * 64))[cq] = r;
        } else if (cq < 32) {
            US4 u = { f2bf(acc[nn][0]), f2bf(acc[nn][1]), f2bf(acc[nn][2]), f2bf(acc[nn][3]) };
            ((US4*)(kb + (size_t)n * 64))[cq - 16] = u;
        } else if (cq < 48) {
            US4 u = { f2bf(acc[nn][0]), f2bf(acc[nn][1]), f2bf(acc[nn][2]), f2bf(acc[nn][3]) };
            ((US4*)(vb + (size_t)n * 64))[cq - 32] = u;
        } else if (cq < 50) {
            float4 r = make_float4(acc[nn][0], acc[nn][1], acc[nn][2], acc[nn][3]);
            ((float4*)(an + (size_t)n * 8))[cq - 48] = r;
        } else {
            float4 r = make_float4(acc[nn][0], acc[nn][1], acc[nn][2], acc[nn][3]);
            ((float4*)(bn + (size_t)n * 8))[cq - 50] = r;
        }
    }
}

// ---------------- temporal profile normalization (ddof=1) -> bf16, one wave per node ----------
__global__ __launch_bounds__(256) void k_tpn(const float* __restrict__ tp,
                                             unsigned short* __restrict__ tpnb, int N)
{
    int wave = threadIdx.x >> 6;
    int lane = threadIdx.x & 63;
    int n = blockIdx.x * 4 + wave;
    if (n >= N) return;
    const float* row = tp + (size_t)n * 96;
    float v0 = row[lane];
    float v1 = (lane < 32) ? row[64 + lane] : 0.f;
    float s = v0 + v1, ss = v0 * v0 + v1 * v1;
    #pragma unroll
    for (int m = 1; m < 64; m <<= 1) { s += __shfl_xor(s, m); ss += __shfl_xor(ss, m); }
    float mean = s * (1.f / 96.f);
    float var = (ss - 96.f * mean * mean) * (1.f / 95.f);
    var = fmaxf(var, 0.f);
    float inv = 1.f / (sqrtf(var) + 1e-8f);
    unsigned short* orow = tpnb + (size_t)n * 96;
    orow[lane] = f2bf((v0 - mean) * inv);
    if (lane < 32) orow[64 + lane] = f2bf((v1 - mean) * inv);
}

// ---------------- CSR build: histogram / scan / scatter ----------------
__global__ __launch_bounds__(256) void k_hist(const int* __restrict__ ei,
                                              int* __restrict__ deg, int E0, int N)
{
    int e = blockIdx.x * 256 + threadIdx.x;
    int E = E0 + N;
    if (e >= E) return;
    int dst = (e < E0) ? ei[E0 + e] : (e - E0);
    atomicAdd(&deg[dst], 1);
}

__global__ __launch_bounds__(1024) void k_scan(const int* __restrict__ deg,
                                               int* __restrict__ row,
                                               int* __restrict__ cursor, int N)
{
    __shared__ int part[1024];
    int t = threadIdx.x;
    int chunk = (N + 1023) >> 10;
    int s0 = t * chunk;
    int s = 0;
    for (int i = 0; i < chunk; i++) {
        int idx = s0 + i;
        if (idx < N) s += deg[idx];
    }
    part[t] = s;
    __syncthreads();
    for (int off = 1; off < 1024; off <<= 1) {
        int vv = (t >= off) ? part[t - off] : 0;
        __syncthreads();
        part[t] += vv;
        __syncthreads();
    }
    int run = (t == 0) ? 0 : part[t - 1];
    for (int i = 0; i < chunk; i++) {
        int idx = s0 + i;
        if (idx < N) { row[idx] = run; cursor[idx] = run; run += deg[idx]; }
    }
    if (t == 1023) row[N] = part[1023];
}

__global__ __launch_bounds__(256) void k_scatter(const int* __restrict__ ei,
                                                 int* __restrict__ cursor,
                                                 int2* __restrict__ csrp, int E0, int N)
{
    int e = blockIdx.x * 256 + threadIdx.x;
    int E = E0 + N;
    if (e >= E) return;
    int src, dst;
    if (e < E0) { src = ei[e]; dst = ei[E0 + e]; }
    else        { src = e - E0; dst = src; }
    int pos = atomicAdd(&cursor[dst], 1);
    csrp[pos] = make_int2(e, src);
}

// ---------------- fused per-node: alpha + online softmax + aggregation + Wo ----------------
// one wave per node; lane = h*8 + c
__global__ __launch_bounds__(256) void k_fused(
    const int2* __restrict__ csrp, const int* __restrict__ row,
    const float* __restrict__ eattr,
    const unsigned short* __restrict__ tpnb, const float* __restrict__ q,
    const unsigned short* __restrict__ kb, const unsigned short* __restrict__ vb,
    const float* __restrict__ an, const float* __restrict__ bn,
    const float* __restrict__ We, const float* __restrict__ comp_b,
    const float* __restrict__ Wo, const float* __restrict__ bo,
    float* __restrict__ out, int E0, int N)
{
    const int tid = threadIdx.x;
    const int wave = tid >> 6, lane = tid & 63;
    const int h = lane >> 3;
    const int n = blockIdx.x * 4 + wave;
    if (n >= N) return;

    // per-lane We row (wet[d] = We[lane][d], d=0..15)  -> kw needs no shuffles
    const float4* wer = (const float4*)(We + (size_t)lane * 16);
    float4 wet0 = wer[0], wet1 = wer[1], wet2 = wer[2], wet3 = wer[3];
    float kw1 = wet0.x + wet0.y + wet0.z + wet0.w + wet1.x + wet1.y + wet1.z + wet1.w
              + wet2.x + wet2.y + wet2.z + wet2.w + wet3.x + wet3.y + wet3.z + wet3.w;

    const int beg = row[n], end = row[n + 1];
    const float qv = q[(size_t)n * 64 + lane] * 0.35355339059327373f;  // 1/sqrt(8) folded
    const float bnh = bn[(size_t)n * 8 + h] + comp_b[h];
    float td0 = 0.f, td1 = 0.f;
    if (lane < 48) {
        unsigned u = *(const unsigned*)(tpnb + (size_t)n * 96 + 2 * lane);
        td0 = __uint_as_float(u << 16);
        td1 = __uint_as_float(u & 0xffff0000u);
    }

    float mh = -1e30f, dsum = 0.f, acc = 0.f;

    int2 ec = csrp[beg];
    for (int idx = beg; idx < end; ++idx) {
        const int e = ec.x, s = ec.y;
        // gathers (src side)
        unsigned tsu = 0;
        if (lane < 48) tsu = *(const unsigned*)(tpnb + (size_t)s * 96 + 2 * lane);
        unsigned short ku = kb[(size_t)s * 64 + lane];
        unsigned short vu = vb[(size_t)s * 64 + lane];
        float anh = an[(size_t)s * 8 + h];
        if (idx + 1 < end) ec = csrp[idx + 1];   // prefetch next edge ids

        float kw;
        if (e < E0) {   // wave-uniform branch
            const float4* ep = (const float4*)(eattr + (size_t)e * 16);
            float4 e0 = ep[0], e1 = ep[1], e2 = ep[2], e3 = ep[3];
            kw = e0.x * wet0.x + e0.y * wet0.y + e0.z * wet0.z + e0.w * wet0.w
               + e1.x * wet1.x + e1.y * wet1.y + e1.z * wet1.z + e1.w * wet1.w
               + e2.x * wet2.x + e2.y * wet2.y + e2.z * wet2.z + e2.w * wet2.w
               + e3.x * wet3.x + e3.y * wet3.y + e3.z * wet3.z + e3.w * wet3.w;
        } else {
            kw = kw1;
        }

        float ts0 = __uint_as_float(tsu << 16);
        float ts1 = __uint_as_float(tsu & 0xffff0000u);
        float cp = ts0 * td0 + ts1 * td1;          // corr partial
        float t = tanhf(anh + bnh);                // same across c within group

        float kf = bf2f(ku);
        float s1 = kf * (qv + kw);                 // qk/sqrt8 + efk partial
        s1 += __shfl_xor(s1, 1); s1 += __shfl_xor(s1, 2); s1 += __shfl_xor(s1, 4);
        cp += __shfl_xor(cp, 1); cp += __shfl_xor(cp, 2); cp += __shfl_xor(cp, 4);
        cp += __shfl_xor(cp, 8);  t += __shfl_xor(t, 8);
        cp += __shfl_xor(cp, 16); t += __shfl_xor(t, 16);
        cp += __shfl_xor(cp, 32); t += __shfl_xor(t, 32);
        // alpha = s1 - 0.25*corr - 0.25*learned ; corr=cp/96, learned=t/8
        float a = s1 - cp * (0.25f / 96.f) - t * (0.25f / 8.f);
        a = (a >= 0.f) ? a : 0.2f * a;             // leaky relu

        // online softmax update (per head, replicated across c)
        float mn = fmaxf(mh, a);
        float sc = __expf(mh - mn);
        float p = __expf(a - mn);
        dsum = dsum * sc + p;
        acc = acc * sc + p * bf2f(vu);
        mh = mn;
    }

    float outv = acc / (dsum + 1e-16f);

    // fused output projection: out[n][cp] = sum_hc outv[hc]*Wo[cp][hc] + bo[cp]
    float po[8];
    #pragma unroll
    for (int cp8 = 0; cp8 < 8; cp8++) po[cp8] = outv * Wo[cp8 * 64 + lane];
    #pragma unroll
    for (int m = 1; m < 64; m <<= 1) {
        #pragma unroll
        for (int cp8 = 0; cp8 < 8; cp8++) po[cp8] += __shfl_xor(po[cp8], m);
    }
    if (lane < 8) out[(size_t)n * 8 + lane] = po[lane] + bo[lane];
}

extern "C" void kernel_launch(void* const* d_in, const int* in_sizes, int n_in,
                              void* d_out, int out_size, void* d_ws, size_t ws_size,
                              hipStream_t stream)
{
    const float* x     = (const float*)d_in[0];
    const int*   ei    = (const int*)d_in[1];
    const float* eattr = (const float*)d_in[2];
    const float* tp    = (const float*)d_in[3];
    const float* Wq    = (const float*)d_in[4];
    const float* Wk    = (const float*)d_in[5];
    const float* Wv    = (const float*)d_in[6];
    const float* We    = (const float*)d_in[7];
    const float* compW = (const float*)d_in[8];
    const float* compb = (const float*)d_in[9];
    const float* Wo    = (const float*)d_in[10];
    const float* bo    = (const float*)d_in[11];
    float* out = (float*)d_out;

    const int N  = in_sizes[0] / 128;
    const int E0 = in_sizes[1] / 2;
    const int E  = E0 + N;

    float* ws = (float*)d_ws;
    size_t off = 0;
    unsigned short* tpnb = (unsigned short*)(ws + off); off += (size_t)N * 48;   // N*96 ushort
    float* q  = ws + off; off += (size_t)N * 64;
    unsigned short* kb = (unsigned short*)(ws + off); off += (size_t)N * 32;     // N*64 ushort
    unsigned short* vb = (unsigned short*)(ws + off); off += (size_t)N * 32;
    float* an = ws + off; off += (size_t)N * 8;
    float* bn = ws + off; off += (size_t)N * 8;
    int* deg    = (int*)(ws + off); off += N;
    int* rowp   = (int*)(ws + off); off += N + 1;
    int* cursor = (int*)(ws + off); off += N;
    int2* csrp  = (int2*)(ws + off); off += (size_t)E * 2;

    hipMemsetAsync(deg, 0, (size_t)N * sizeof(int), stream);

    k_hist<<<(E + 255) / 256, 256, 0, stream>>>(ei, deg, E0, N);
    k_scan<<<1, 1024, 0, stream>>>(deg, rowp, cursor, N);
    k_scatter<<<(E + 255) / 256, 256, 0, stream>>>(ei, cursor, csrp, E0, N);

    k_proj<<<(N + 63) / 64, 256, 0, stream>>>(x, Wq, Wk, Wv, compW, q, kb, vb, an, bn, N);
    k_tpn<<<(N + 3) / 4, 256, 0, stream>>>(tp, tpnb, N);
    k_fused<<<(N + 3) / 4, 256, 0, stream>>>(csrp, rowp, eattr, tpnb, q, kb, vb, an, bn,
                                             We, compb, Wo, bo, out, E0, N);
}